// Round 3
// baseline (142.838 us; speedup 1.0000x reference)
//
#include <hip/hip_runtime.h>

// Problem constants
#define B_  128
#define I_  64
#define P_  16
#define T_  5
#define NT  3
#define VOCAB 100000
#define D_  64
#define NPAIR (B_ * I_)        // 8192 (n)
#define OUTROWS NPAIR          // 8192 output rows of 64

// ---------- bf16 helpers ----------
__device__ __forceinline__ unsigned short f2b(float f) {
    unsigned int u = __float_as_uint(f);
    return (unsigned short)((u + 0x7fffu + ((u >> 16) & 1u)) >> 16);   // RNE
}

typedef short short8 __attribute__((ext_vector_type(8)));
typedef float f32x4 __attribute__((ext_vector_type(4)));

// bf16 row stride in LDS = 128 B (exact row size) + XOR swizzle for banks.
// swizzle: byte offset within row ^= (row & 7) << 4  (bits 4-6, 16B-granular,
// bijective; preserves 8B store / 16B load alignment). Verified passing in R2.
#define AROW_STRIDE 128
#define AWAVE_BYTES (80 * AROW_STRIDE)   // 10240/wave -> 40960/block -> 4 blocks/CU

// =====================================================================
// wprep: bf16 weight fragments in EXACT mfma first-operand lane order.
// Entry e = ((cb*2+half)*4+quad)*16 + m holds 8 shorts (16B):
//   channel c = cb*16+m, k = half*32 + quad*8 + j
//   cb<4 -> W0[c][k] = convw[c*128 + 2k] ; cb>=4 -> W1[c-64][k] = convw[..+1]
// =====================================================================
__global__ __launch_bounds__(256) void wprep(
        const float* __restrict__ convw, unsigned short* __restrict__ Wf) {
    const int e0 = threadIdx.x * 4;
#pragma unroll
    for (int e = e0; e < e0 + 4; ++e) {
        int m = e & 15;
        int quad = (e >> 4) & 3;
        int half = (e >> 6) & 1;
        int cb = e >> 7;
        int c = cb * 16 + m;
        const float* wp = (c < 64) ? (convw + c * 128) : (convw + (c - 64) * 128 + 1);
#pragma unroll
        for (int j = 0; j < 8; ++j) {
            int k = half * 32 + quad * 8 + j;
            Wf[e * 8 + j] = f2b(wp[k * 2]);
        }
    }
}

// =====================================================================
// FUSED kernel. One wave per output row nn.
// Gather phase: instruction i reads 4 table rows FULLY CONTIGUOUSLY:
//   lane (r2=lane>>4, c16=lane&15) reads row (t=i>>2, pp=(i&3)*4+r2),
//   bytes [c16*16, +16) -> 8 fully-used 128B segments per instruction.
// KEY register-budget move (fix of R2's spill regression): gathers use
// saddr + 32-bit byte voffset (boff[20], max 76.8MB < 2^32) so the gather
// loop's live set is boff(20)+F(80)+misc ~= 110 regs -> fits the 128-reg
// cap of __launch_bounds__(256,4) with NO spills, keeping all 20 loads
// in flight. 40KB LDS/block -> 4 blocks/CU = 16 waves/CU.
// Weight fragments loaded ns-outer AFTER staging (16 VGPRs live, L1-hot).
// =====================================================================
__global__ __launch_bounds__(256, 4) void fused_path(
        const int* __restrict__ path_input, const int* __restrict__ path_type,
        const float* __restrict__ tables, const unsigned short* __restrict__ Wf,
        const float* __restrict__ bias, float* __restrict__ out) {
    __shared__ __align__(16) unsigned char Asmem[4][AWAVE_BYTES];   // 40960 B
    const int tid = threadIdx.x;
    const int w = tid >> 6;
    const int lane = tid & 63;
    const int l16 = lane & 15;      // pp (compute phase) / c16 (gather phase)
    const int quad = lane >> 4;
    const int r2 = lane >> 4;       // row-within-group (gather phase): 0..3
    const int c16 = lane & 15;      // 16B chunk within row (gather phase)

    const int nn = blockIdx.x * 4 + w;
    const int g = nn >> 4, q = nn & 15;
    unsigned char* myA = Asmem[w];
    const unsigned char* tb = (const unsigned char*)tables;

    // ---- per-instruction row BYTE offsets (32-bit; broadcast over c16) ----
    unsigned int boff[20];
#pragma unroll
    for (int i = 0; i < 20; ++i) {
        int t = i >> 2, sub = i & 3;
        int pp = sub * 4 + r2;
        int addr = ((pp * 512 + g) * 16 + q) * 5 + t;
        boff[i] = ((unsigned int)(path_type[t] * VOCAB + path_input[addr])) * 256u
                + (unsigned int)(c16 * 16);
    }

    // ---- dense gathers: saddr + u32 voffset, 16B contiguous per lane ----
    float4 F[20];
#pragma unroll
    for (int i = 0; i < 20; ++i)
        F[i] = *(const float4*)(tb + (unsigned long long)boff[i]);

    // ---- convert + stage to LDS (bf16, swizzled, per-wave region) ----
#pragma unroll
    for (int i = 0; i < 20; ++i) {
        int t = i >> 2, sub = i & 3;
        int R = t * 16 + sub * 4 + r2;
        unsigned int p0 = (unsigned int)f2b(F[i].x) | ((unsigned int)f2b(F[i].y) << 16);
        unsigned int p1 = (unsigned int)f2b(F[i].z) | ((unsigned int)f2b(F[i].w) << 16);
        uint2 pk; pk.x = p0; pk.y = p1;
        int off = (c16 * 8) ^ ((R & 7) << 4);
        *(uint2*)(myA + R * AROW_STRIDE + off) = pk;
    }

    // ---- read MFMA A-fragments: lane (l16,quad), k = [half*32 + quad*8 + j) ----
    short8 A0[5], A1[5];
#pragma unroll
    for (int t = 0; t < 5; ++t) {
        const unsigned char* rp = myA + (t * 16 + l16) * AROW_STRIDE;
        int sw = (l16 & 7) << 4;                           // (row&7)<<4
        A0[t] = *(const short8*)(rp + ((quad * 16) ^ sw));        // bf16 k 0..31
        A1[t] = *(const short8*)(rp + ((64 + quad * 16) ^ sw));   // bf16 k 32..63
    }

    // ---- windows: runmax over to of U_to + V_{to+1}; ns-outer, Wf per-ns ----
    f32x4 runmax[4];
#pragma unroll
    for (int ns = 0; ns < 4; ++ns) {
        // weight fragments for this ns only (16 VGPRs live, L1-hot 16KB buffer)
        short8 W0lo = *(const short8*)&Wf[((ns * 8 + 0 + quad) * 16 + l16) * 8];
        short8 W0hi = *(const short8*)&Wf[((ns * 8 + 4 + quad) * 16 + l16) * 8];
        short8 W1lo = *(const short8*)&Wf[(((ns + 4) * 8 + 0 + quad) * 16 + l16) * 8];
        short8 W1hi = *(const short8*)&Wf[(((ns + 4) * 8 + 4 + quad) * 16 + l16) * 8];
        f32x4 rm = {-1e30f, -1e30f, -1e30f, -1e30f};
#pragma unroll
        for (int to = 0; to < 4; ++to) {
            f32x4 uu = {0.f, 0.f, 0.f, 0.f};
            uu = __builtin_amdgcn_mfma_f32_16x16x32_bf16(W0lo, A0[to], uu, 0, 0, 0);
            uu = __builtin_amdgcn_mfma_f32_16x16x32_bf16(W0hi, A1[to], uu, 0, 0, 0);
            f32x4 vv = {0.f, 0.f, 0.f, 0.f};
            vv = __builtin_amdgcn_mfma_f32_16x16x32_bf16(W1lo, A0[to + 1], vv, 0, 0, 0);
            vv = __builtin_amdgcn_mfma_f32_16x16x32_bf16(W1hi, A1[to + 1], vv, 0, 0, 0);
#pragma unroll
            for (int j = 0; j < 4; ++j)
                rm[j] = fmaxf(rm[j], uu[j] + vv[j]);
        }
        runmax[ns] = rm;
    }

    // ---- max over pp = max over the 16 D-columns (lanes l16) ----
#pragma unroll
    for (int ns = 0; ns < 4; ++ns) {
#pragma unroll
        for (int j = 0; j < 4; ++j) {
            float v = runmax[ns][j];
            v = fmaxf(v, __shfl_xor(v, 1));
            v = fmaxf(v, __shfl_xor(v, 2));
            v = fmaxf(v, __shfl_xor(v, 4));
            v = fmaxf(v, __shfl_xor(v, 8));
            runmax[ns][j] = v;
        }
    }
    if (l16 == 0) {
        // lane (0, quad) holds channels ns*16 + quad*4 + j
#pragma unroll
        for (int ns = 0; ns < 4; ++ns) {
            int c = ns * 16 + quad * 4;
            float4 bv = *(const float4*)(bias + c);
            float4 o;
            o.x = runmax[ns][0] + bv.x;
            o.y = runmax[ns][1] + bv.y;
            o.z = runmax[ns][2] + bv.z;
            o.w = runmax[ns][3] + bv.w;
            *(float4*)(out + (size_t)nn * 64 + c) = o;
        }
    }
}

// =====================================================================
// Fallback (if workspace too small): direct fused fp32.
// =====================================================================
__global__ __launch_bounds__(64) void fused_direct(
        const int* __restrict__ path_input, const int* __restrict__ path_type,
        const float* __restrict__ tables, const float* __restrict__ convw,
        const float* __restrict__ bias, float* __restrict__ out) {
    const int nn = blockIdx.x;
    const int o = threadIdx.x;
    const int g = nn >> 4;
    const int q = nn & 15;
    float w0[64], w1[64];
#pragma unroll
    for (int i = 0; i < 64; ++i) {
        w0[i] = convw[o * 128 + i * 2];
        w1[i] = convw[o * 128 + i * 2 + 1];
    }
    int tb[5];
#pragma unroll
    for (int t = 0; t < 5; ++t) tb[t] = path_type[t] * VOCAB;
    __shared__ float emb[5][64];
    float acc = -1e30f;
    for (int pp = 0; pp < 16; ++pp) {
        int m = pp * 512 + g;
        const int* ip = path_input + ((m * 16 + q) * 5);
        __syncthreads();
#pragma unroll
        for (int t = 0; t < 5; ++t)
            emb[t][o] = tables[(size_t)(tb[t] + ip[t]) * 64 + o];
        __syncthreads();
#pragma unroll
        for (int to = 0; to < 4; ++to) {
            float s = 0.f;
#pragma unroll
            for (int i = 0; i < 64; ++i)
                s += w0[i] * emb[to][i] + w1[i] * emb[to + 1][i];
            acc = fmaxf(acc, s);
        }
    }
    out[(size_t)nn * 64 + o] = acc + bias[o];
}

extern "C" void kernel_launch(void* const* d_in, const int* in_sizes, int n_in,
                              void* d_out, int out_size, void* d_ws, size_t ws_size,
                              hipStream_t stream) {
    const int*   path_input = (const int*)d_in[0];
    const int*   path_type  = (const int*)d_in[1];
    const float* tables     = (const float*)d_in[2];
    const float* convw      = (const float*)d_in[3];
    const float* convb      = (const float*)d_in[4];
    float* out = (float*)d_out;

    const size_t needWf = (size_t)16 * 1024 * sizeof(unsigned short);   // 32 KB
    if (ws_size >= needWf) {
        unsigned short* Wf = (unsigned short*)d_ws;
        wprep<<<1, 256, 0, stream>>>(convw, Wf);
        fused_path<<<OUTROWS / 4, 256, 0, stream>>>(path_input, path_type,
                                                    tables, Wf, convb, out);
    } else {
        fused_direct<<<OUTROWS, 64, 0, stream>>>(path_input, path_type, tables, convw, convb, out);
    }
}

// Round 4
// 132.879 us; speedup vs baseline: 1.0750x; 1.0750x over previous
//
#include <hip/hip_runtime.h>
#include <hip/hip_bf16.h>

// Problem constants
#define B_  128
#define I_  64
#define P_  16
#define T_  5
#define NT  3
#define VOCAB 100000
#define D_  64
#define NPAIR (B_ * I_)        // 8192 (n)
#define OUTROWS NPAIR          // 8192 output rows of 64

// ---------- bf16 helpers ----------
__device__ __forceinline__ unsigned short f2b(float f) {
    unsigned int u = __float_as_uint(f);
    return (unsigned short)((u + 0x7fffu + ((u >> 16) & 1u)) >> 16);   // RNE
}

typedef short short8 __attribute__((ext_vector_type(8)));
typedef float f32x4 __attribute__((ext_vector_type(4)));

#define AROW_STRIDE 160        // bf16 row stride in LDS bytes (16B-aligned)
#define AWAVE_BYTES (80 * AROW_STRIDE)   // 12800 per wave

// =====================================================================
// wprep: bf16 weight fragments in EXACT mfma first-operand lane order.
// Entry e = ((cb*2+half)*4+quad)*16 + m holds 8 shorts (16B):
//   channel c = cb*16+m, k = half*32 + quad*8 + j
//   cb<4 -> W0[c][k] = convw[c*128 + 2k] ; cb>=4 -> W1[c-64][k] = convw[..+1]
// =====================================================================
__global__ __launch_bounds__(256) void wprep(
        const float* __restrict__ convw, unsigned short* __restrict__ Wf) {
    const int e0 = threadIdx.x * 4;
#pragma unroll
    for (int e = e0; e < e0 + 4; ++e) {
        int m = e & 15;
        int quad = (e >> 4) & 3;
        int half = (e >> 6) & 1;
        int cb = e >> 7;
        int c = cb * 16 + m;
        const float* wp = (c < 64) ? (convw + c * 128) : (convw + (c - 64) * 128 + 1);
#pragma unroll
        for (int j = 0; j < 8; ++j) {
            int k = half * 32 + quad * 8 + j;
            Wf[e * 8 + j] = f2b(wp[k * 2]);
        }
    }
}

// =====================================================================
// FUSED kernel — verified R0 structure (best measured: 132.3 us total),
// with ONE change: gathers use saddr + 32-bit byte voffset (boff[20],
// max 76.8MB < 2^32). Saves 20 64-bit address pairs (~40 VGPRs) and the
// per-load widen/shift VALU work in the gather loop. Everything else
// (stride-160 LDS, weights up-front, no launch-bounds min, compute and
// reduce) is byte-identical to the verified kernel.
// One wave per output row nn. Gather: instruction i reads 4 rows FULLY
// CONTIGUOUSLY: lane (r2=lane>>4, c16=lane&15) reads row (t=i>>2,
// pp=(i&3)*4+r2), bytes [c16*16,+16) -> 8 fully-used 128B segments.
// =====================================================================
__global__ __launch_bounds__(256) void fused_path(
        const int* __restrict__ path_input, const int* __restrict__ path_type,
        const float* __restrict__ tables, const unsigned short* __restrict__ Wf,
        const float* __restrict__ bias, float* __restrict__ out) {
    __shared__ __align__(16) unsigned char Asmem[4][AWAVE_BYTES];   // 51200 B
    const int tid = threadIdx.x;
    const int w = tid >> 6;
    const int lane = tid & 63;
    const int l16 = lane & 15;      // pp (compute phase) / c16 (gather phase)
    const int quad = lane >> 4;
    const int r2 = lane >> 4;       // row-within-group (gather phase): 0..3
    const int c16 = lane & 15;      // 16B chunk within row (gather phase)

    const int nn = blockIdx.x * 4 + w;
    const int g = nn >> 4, q = nn & 15;
    unsigned char* myA = Asmem[w];
    const unsigned char* tbp = (const unsigned char*)tables;

    // ---- weight fragments (16KB buffer, L1/L2-resident) ----
    short8 WB0[8], WB1[8];
#pragma unroll
    for (int ns = 0; ns < 8; ++ns) {
        WB0[ns] = *(const short8*)&Wf[((ns * 8 + 0 + quad) * 16 + l16) * 8];
        WB1[ns] = *(const short8*)&Wf[((ns * 8 + 4 + quad) * 16 + l16) * 8];
    }

    // ---- per-instruction row BYTE offsets (32-bit; broadcast over c16) ----
    unsigned int boff[20];
#pragma unroll
    for (int i = 0; i < 20; ++i) {
        int t = i >> 2, sub = i & 3;
        int pp = sub * 4 + r2;
        int addr = ((pp * 512 + g) * 16 + q) * 5 + t;
        boff[i] = ((unsigned int)(path_type[t] * VOCAB + path_input[addr])) * 256u
                + (unsigned int)(c16 * 16);
    }

    // ---- dense gathers: saddr + u32 voffset, 16B contiguous per lane ----
    float4 F[20];
#pragma unroll
    for (int i = 0; i < 20; ++i)
        F[i] = *(const float4*)(tbp + (size_t)boff[i]);

    // ---- convert + stage to LDS (bf16, per-wave region, no barrier) ----
#pragma unroll
    for (int i = 0; i < 20; ++i) {
        int t = i >> 2, sub = i & 3;
        int R = t * 16 + sub * 4 + r2;
        unsigned int p0 = (unsigned int)f2b(F[i].x) | ((unsigned int)f2b(F[i].y) << 16);
        unsigned int p1 = (unsigned int)f2b(F[i].z) | ((unsigned int)f2b(F[i].w) << 16);
        uint2 pk; pk.x = p0; pk.y = p1;
        *(uint2*)(myA + R * AROW_STRIDE + c16 * 8) = pk;
    }

    // ---- read MFMA A-fragments: lane (l16,quad), k = [half*32 + quad*8 + j) ----
    short8 A0[5], A1[5];
#pragma unroll
    for (int t = 0; t < 5; ++t) {
        const unsigned char* rp = myA + (t * 16 + l16) * AROW_STRIDE;
        A0[t] = *(const short8*)(rp + quad * 16);          // bf16 k 0..31
        A1[t] = *(const short8*)(rp + 64 + quad * 16);     // bf16 k 32..63
    }

    // ---- windows: runmax over to of U_to + V_{to+1} ----
    f32x4 runmax[4];
#pragma unroll
    for (int ns = 0; ns < 4; ++ns) runmax[ns] = (f32x4){-1e30f, -1e30f, -1e30f, -1e30f};
#pragma unroll
    for (int to = 0; to < 4; ++to) {
#pragma unroll
        for (int ns = 0; ns < 4; ++ns) {
            f32x4 uu = {0.f, 0.f, 0.f, 0.f};
            uu = __builtin_amdgcn_mfma_f32_16x16x32_bf16(WB0[ns], A0[to], uu, 0, 0, 0);
            uu = __builtin_amdgcn_mfma_f32_16x16x32_bf16(WB1[ns], A1[to], uu, 0, 0, 0);
            f32x4 vv = {0.f, 0.f, 0.f, 0.f};
            vv = __builtin_amdgcn_mfma_f32_16x16x32_bf16(WB0[ns + 4], A0[to + 1], vv, 0, 0, 0);
            vv = __builtin_amdgcn_mfma_f32_16x16x32_bf16(WB1[ns + 4], A1[to + 1], vv, 0, 0, 0);
#pragma unroll
            for (int j = 0; j < 4; ++j)
                runmax[ns][j] = fmaxf(runmax[ns][j], uu[j] + vv[j]);
        }
    }

    // ---- max over pp = max over the 16 D-columns (lanes l16) ----
#pragma unroll
    for (int ns = 0; ns < 4; ++ns) {
#pragma unroll
        for (int j = 0; j < 4; ++j) {
            float v = runmax[ns][j];
            v = fmaxf(v, __shfl_xor(v, 1));
            v = fmaxf(v, __shfl_xor(v, 2));
            v = fmaxf(v, __shfl_xor(v, 4));
            v = fmaxf(v, __shfl_xor(v, 8));
            runmax[ns][j] = v;
        }
    }
    if (l16 == 0) {
        // lane (0, quad) holds channels ns*16 + quad*4 + j
#pragma unroll
        for (int ns = 0; ns < 4; ++ns) {
            int c = ns * 16 + quad * 4;
            float4 bv = *(const float4*)(bias + c);
            float4 o;
            o.x = runmax[ns][0] + bv.x;
            o.y = runmax[ns][1] + bv.y;
            o.z = runmax[ns][2] + bv.z;
            o.w = runmax[ns][3] + bv.w;
            *(float4*)(out + (size_t)nn * 64 + c) = o;
        }
    }
}

// =====================================================================
// Fallback (if workspace too small): direct fused fp32.
// =====================================================================
__global__ __launch_bounds__(64) void fused_direct(
        const int* __restrict__ path_input, const int* __restrict__ path_type,
        const float* __restrict__ tables, const float* __restrict__ convw,
        const float* __restrict__ bias, float* __restrict__ out) {
    const int nn = blockIdx.x;
    const int o = threadIdx.x;
    const int g = nn >> 4;
    const int q = nn & 15;
    float w0[64], w1[64];
#pragma unroll
    for (int i = 0; i < 64; ++i) {
        w0[i] = convw[o * 128 + i * 2];
        w1[i] = convw[o * 128 + i * 2 + 1];
    }
    int tb[5];
#pragma unroll
    for (int t = 0; t < 5; ++t) tb[t] = path_type[t] * VOCAB;
    __shared__ float emb[5][64];
    float acc = -1e30f;
    for (int pp = 0; pp < 16; ++pp) {
        int m = pp * 512 + g;
        const int* ip = path_input + ((m * 16 + q) * 5);
        __syncthreads();
#pragma unroll
        for (int t = 0; t < 5; ++t)
            emb[t][o] = tables[(size_t)(tb[t] + ip[t]) * 64 + o];
        __syncthreads();
#pragma unroll
        for (int to = 0; to < 4; ++to) {
            float s = 0.f;
#pragma unroll
            for (int i = 0; i < 64; ++i)
                s += w0[i] * emb[to][i] + w1[i] * emb[to + 1][i];
            acc = fmaxf(acc, s);
        }
    }
    out[(size_t)nn * 64 + o] = acc + bias[o];
}

extern "C" void kernel_launch(void* const* d_in, const int* in_sizes, int n_in,
                              void* d_out, int out_size, void* d_ws, size_t ws_size,
                              hipStream_t stream) {
    const int*   path_input = (const int*)d_in[0];
    const int*   path_type  = (const int*)d_in[1];
    const float* tables     = (const float*)d_in[2];
    const float* convw      = (const float*)d_in[3];
    const float* convb      = (const float*)d_in[4];
    float* out = (float*)d_out;

    const size_t needWf = (size_t)16 * 1024 * sizeof(unsigned short);   // 32 KB
    if (ws_size >= needWf) {
        unsigned short* Wf = (unsigned short*)d_ws;
        wprep<<<1, 256, 0, stream>>>(convw, Wf);
        fused_path<<<OUTROWS / 4, 256, 0, stream>>>(path_input, path_type,
                                                    tables, Wf, convb, out);
    } else {
        fused_direct<<<OUTROWS, 64, 0, stream>>>(path_input, path_type, tables, convw, convb, out);
    }
}